// Round 1
// 96.573 us; speedup vs baseline: 1.0585x; 1.0585x over previous
//
#include <hip/hip_runtime.h>

// Bilateral filter denoiser: K=5, sigma_s=2.0, sigma_r=0.1, B=8,C=3,H=512,W=512, fp32.
// weight(dy,dx) = exp(-(n-c)^2/(2*0.1^2)) * exp(-(dx^2+dy^2)/8)
//              = exp2( RC*(n-c)^2 + L[r2] ),  r2 = (dy-2)^2+(dx-2)^2, L[r2] = -r2*log2(e)/8
// RC*(n-c)^2 + L computed as fma(fma(RC,n,B), n, C0L), B=-2RC*c, C0L=RC*c^2 + L (2 FMAs/tap,
// spatial mul folded into the exponent constant -- 5 distinct L values, hoisted per pixel).
// 4 px/thread as two float2 halves -> v_pk_* packed fp32 ops.
// LDS rows are 72 words (288B, 16B-aligned) with halo at cols 0-1, so every window read is
// two aligned ds_read_b128; center values come from the dy=2 row load (no extra read).
// Center tap: weight == 1 exactly -> ws init 1, acc init c; ws>=1 so no clip, rcp ok.
// Staging vectorized as float2 (rows of 68 = 34 float2), scalar reflect fallback only for
// edge columns of x-border blocks; y-reflect is a per-row index remap.

#define KK 5
#define HALO 2
#define TX 64          // tile width (pixels)
#define TY 16          // tile height
#define PXT 4          // pixels per thread along x
#define LW (TX + 2*HALO)   // 68 data columns
#define LH (TY + 2*HALO)   // 20 rows
#define LSTRIDE 72         // 288B rows: 16B-aligned, cols 68..71 unused
#define IMG_H 512
#define IMG_W 512

typedef float v2f __attribute__((ext_vector_type(2)));
typedef float v4f __attribute__((ext_vector_type(4)));

#if defined(__has_builtin)
#if __has_builtin(__builtin_amdgcn_exp2f)
#define FAST_EXP2(x) __builtin_amdgcn_exp2f(x)
#else
#define FAST_EXP2(x) exp2f(x)
#endif
#if __has_builtin(__builtin_amdgcn_rcpf)
#define FAST_RCP(x) __builtin_amdgcn_rcpf(x)
#else
#define FAST_RCP(x) (1.0f / (x))
#endif
#else
#define FAST_EXP2(x) exp2f(x)
#define FAST_RCP(x) (1.0f / (x))
#endif

__device__ __forceinline__ int reflect_idx(int i, int n) {
    i = (i < 0) ? -i : i;
    i = (i >= n) ? (2 * n - 2 - i) : i;
    return i;
}

__global__ __launch_bounds__(256, 4)
void bilateral_kernel(const float* __restrict__ x, float* __restrict__ out) {
    __shared__ alignas(16) float tile[LH * LSTRIDE];

    const int tid = threadIdx.x;
    const int tileX0 = blockIdx.x * TX;
    const int tileY0 = blockIdx.y * TY;
    const int img = blockIdx.z;
    const float* __restrict__ src = x + (size_t)img * (IMG_H * IMG_W);
    float* __restrict__ dst = out + (size_t)img * (IMG_H * IMG_W);

    // ---- stage halo tile into LDS, float2-vectorized, reflect padding ----
    // rows of 68 floats = 34 float2 units; 20*34 = 680 units over 256 threads.
    const int NUNITS = LH * (LW / 2);
    for (int u = tid; u < NUNITS; u += 256) {
        int r = u / (LW / 2);            // const divide -> magic mul
        int c2 = u - r * (LW / 2);
        int c = c2 * 2;
        int gy = reflect_idx(tileY0 - HALO + r, IMG_H);
        const float* __restrict__ srow = src + gy * IMG_W;
        int gx0 = tileX0 - HALO + c;
        float2 v;
        if (gx0 >= 0 && gx0 + 1 < IMG_W) {
            v = *reinterpret_cast<const float2*>(&srow[gx0]);   // 8B-aligned (gx0 even)
        } else {
            v.x = srow[reflect_idx(gx0, IMG_W)];
            v.y = srow[reflect_idx(gx0 + 1, IMG_W)];
        }
        *reinterpret_cast<float2*>(&tile[r * LSTRIDE + c]) = v; // 8B-aligned (c even)
    }
    __syncthreads();

    const int txg = tid & 15;      // thread x-group: 0..15
    const int ty  = tid >> 4;      // thread row:     0..15
    const int lx0 = txg * PXT;     // first window word of this thread (halo frame col)

    const float RC = -72.13475204444817f;        // -1/(2*0.1^2) * log2(e)
    // L[r2] = -r2 * log2(e)/8, r2 in {1,2,4,5,8}
    const float L1 = -0.18033688011112043f;
    const float L2 = -0.36067376022224086f;
    const float L4 = -0.7213475204444817f;
    const float L5 = -0.9016844005556021f;
    const float L8 = -1.4426950408889634f;
    const v2f RCv = {RC, RC};

    // aligned b128 row reads: window words w..w+7 at (ty+dy)*72 + lx0 (16B-aligned)
    auto ldrow = [&](int dy, v4f& Q0, v4f& Q1) {
        const v4f* p = reinterpret_cast<const v4f*>(&tile[(ty + dy) * LSTRIDE + lx0]);
        Q0 = p[0];
        Q1 = p[1];
    };

    // center row (dy=2): pixels are words w+2..w+5
    v4f Q20, Q21;
    ldrow(2, Q20, Q21);
    const v2f cA = {Q20[2], Q20[3]};
    const v2f cB = {Q21[0], Q21[1]};

    // per-pixel exponent-poly coefficients: arg = RC*n^2 + B*n + (C0 + L[r2])
    const v2f BA = cA * (-2.0f * RC);
    const v2f BB = cB * (-2.0f * RC);
    const v2f C0A = (cA * cA) * RC;
    const v2f C0B = (cB * cB) * RC;
    const v2f C1A = C0A + L1, C1B = C0B + L1;
    const v2f C2A = C0A + L2, C2B = C0B + L2;
    const v2f C4A = C0A + L4, C4B = C0B + L4;
    const v2f C5A = C0A + L5, C5B = C0B + L5;
    const v2f C8A = C0A + L8, C8B = C0B + L8;

    // center tap folded in: weight exactly 1
    v2f wsA = {1.0f, 1.0f}, wsB = {1.0f, 1.0f};
    v2f accA = cA, accB = cB;

    auto tap = [&](v2f nA, v2f nB, v2f CA, v2f CB) {
        v2f uA = __builtin_elementwise_fma(RCv, nA, BA);
        v2f tA = __builtin_elementwise_fma(uA, nA, CA);
        v2f uB = __builtin_elementwise_fma(RCv, nB, BB);
        v2f tB = __builtin_elementwise_fma(uB, nB, CB);
        v2f eA, eB;
        eA.x = FAST_EXP2(tA.x); eA.y = FAST_EXP2(tA.y);
        eB.x = FAST_EXP2(tB.x); eB.y = FAST_EXP2(tB.y);
        wsA += eA;
        wsB += eB;
        accA = __builtin_elementwise_fma(eA, nA, accA);
        accB = __builtin_elementwise_fma(eB, nB, accB);
    };

    auto dorow = [&](v4f Q0, v4f Q1, v2f CaA, v2f CaB, v2f CbA, v2f CbB,
                     v2f CcA, v2f CcB, bool center_row) {
        v2f P0 = {Q0[0], Q0[1]};
        v2f P1 = {Q0[2], Q0[3]};
        v2f P2 = {Q1[0], Q1[1]};
        v2f P3 = {Q1[2], Q1[3]};
        v2f O0 = {Q0[1], Q0[2]};
        v2f O1 = {Q0[3], Q1[0]};
        v2f O2 = {Q1[1], Q1[2]};
        tap(P0, P1, CaA, CaB);             // dx = 0
        tap(O0, O1, CbA, CbB);             // dx = 1
        if (!center_row) tap(P1, P2, CcA, CcB);  // dx = 2 (non-center rows)
        tap(O1, O2, CbA, CbB);             // dx = 3
        tap(P2, P3, CaA, CaB);             // dx = 4
    };

    // dy = 2 first (row already loaded): r2 = {4,1,-,1,4}
    dorow(Q20, Q21, C4A, C4B, C1A, C1B, C1A, C1B, true);

    #pragma unroll
    for (int dy = 0; dy < KK; dy++) {
        if (dy == 2) continue;
        v4f Q0, Q1;
        ldrow(dy, Q0, Q1);
        if (dy == 0 || dy == 4) {
            // r2 = {8,5,4,5,8}
            dorow(Q0, Q1, C8A, C8B, C5A, C5B, C4A, C4B, false);
        } else {
            // r2 = {5,2,1,2,5}
            dorow(Q0, Q1, C5A, C5B, C2A, C2B, C1A, C1B, false);
        }
    }

    const int ox = tileX0 + lx0;
    const int oy = tileY0 + ty;
    float4 o;
    o.x = accA.x * FAST_RCP(wsA.x);   // ws >= 1 (center tap), clip(1e-10) is dead
    o.y = accA.y * FAST_RCP(wsA.y);
    o.z = accB.x * FAST_RCP(wsB.x);
    o.w = accB.y * FAST_RCP(wsB.y);
    *reinterpret_cast<float4*>(&dst[oy * IMG_W + ox]) = o;
}

extern "C" void kernel_launch(void* const* d_in, const int* in_sizes, int n_in,
                              void* d_out, int out_size, void* d_ws, size_t ws_size,
                              hipStream_t stream) {
    const float* x = (const float*)d_in[0];
    // d_in[1] (spatial 5x5) is analytically exp(-(dx^2+dy^2)/8); folded into constants.
    float* out = (float*)d_out;

    const int n_img = out_size / (IMG_H * IMG_W);   // B*C = 24
    dim3 grid(IMG_W / TX, IMG_H / TY, n_img);       // (8, 32, 24)
    dim3 block(256);
    hipLaunchKernelGGL(bilateral_kernel, grid, block, 0, stream, x, out);
}

// Round 2
// 94.605 us; speedup vs baseline: 1.0805x; 1.0208x over previous
//
#include <hip/hip_runtime.h>
#include <stdint.h>

// Bilateral filter denoiser: K=5, sigma_s=2.0, sigma_r=0.1, B=8,C=3,H=512,W=512, fp32.
// weight(dy,dx) = exp(-(n-c)^2/(2*0.1^2)) * exp(-(dx^2+dy^2)/8)
//              = exp2( RC*(n-c)^2 + L[r2] ),  r2 = (dy-2)^2+(dx-2)^2, L[r2] = -r2*log2(e)/8
// arg computed as fma(fma(RC,n,B), n, C0L), B=-2RC*c, C0L=RC*c^2 + L (2 FMAs/tap, spatial
// weight folded into the exponent constant -- 5 distinct L values hoisted per pixel).
// 4 px/thread as two float2 halves -> v_pk_* packed fp32 ops.
//
// Staging: async global->LDS via __builtin_amdgcn_global_load_lds width=16.
// Tile rows are 72 words (288B = 18x16B units) covering gx in [tileX0-4, tileX0+68):
//   - rows 16B-aligned, LDS written linearly (wave-uniform base + lane*16) as HW requires
//   - per-lane global address handles y-reflect; x is CLAMPED to [0,508] (garbage columns
//     are outside the compute window except 2 cols on x-border blocks, fixed up scalar)
//   - 360 units total = 2 gload_lds instrs/wave (64 + 26 active lanes)
// Compute window for thread = words [txg*4+2, txg*4+10): three aligned ds_read_b128
// (Q0,Q1,Q2); center pixels are exactly Q1.
// Center tap: weight == 1 exactly -> ws init 1, acc init c; ws>=1 so no clip, rcp ok.

#define KK 5
#define HALO 2
#define TX 64          // tile width (pixels)
#define TY 16          // tile height
#define PXT 4          // pixels per thread along x
#define LW 72          // staged words per row: [tileX0-4, tileX0+68)
#define LH (TY + 2*HALO)   // 20 rows
#define LSTRIDE 72         // 288B rows, 16B-aligned
#define UNITS_PER_ROW 18   // 72 words / 4
#define NUNITS (LH * UNITS_PER_ROW)  // 360
#define IMG_H 512
#define IMG_W 512

typedef float v2f __attribute__((ext_vector_type(2)));
typedef float v4f __attribute__((ext_vector_type(4)));

#if defined(__has_builtin)
#if __has_builtin(__builtin_amdgcn_exp2f)
#define FAST_EXP2(x) __builtin_amdgcn_exp2f(x)
#else
#define FAST_EXP2(x) exp2f(x)
#endif
#if __has_builtin(__builtin_amdgcn_rcpf)
#define FAST_RCP(x) __builtin_amdgcn_rcpf(x)
#else
#define FAST_RCP(x) (1.0f / (x))
#endif
#if __has_builtin(__builtin_amdgcn_global_load_lds)
#define HAVE_GLOAD_LDS 1
#endif
#else
#define FAST_EXP2(x) exp2f(x)
#define FAST_RCP(x) (1.0f / (x))
#endif

__device__ __forceinline__ int reflect_idx(int i, int n) {
    i = (i < 0) ? -i : i;
    i = (i >= n) ? (2 * n - 2 - i) : i;
    return i;
}

#ifdef HAVE_GLOAD_LDS
__device__ __forceinline__ void async_copy16(const float* g, float* l) {
    // generic->AS(1) cast for global src; LDS ptr via 32-bit truncation (flat LDS
    // addresses are aperture|offset with 4GB-aligned aperture -> low 32 bits = offset,
    // same semantics LLVM uses for flat->local addrspacecast).
    auto gp = (const __attribute__((address_space(1))) void*)g;
    auto lp = (__attribute__((address_space(3))) void*)(uint32_t)(uintptr_t)l;
    __builtin_amdgcn_global_load_lds(gp, lp, 16, 0, 0);
}
#endif

__global__ __launch_bounds__(256, 4)
void bilateral_kernel(const float* __restrict__ x, float* __restrict__ out) {
    __shared__ alignas(16) float tile[LH * LSTRIDE];

    const int tid = threadIdx.x;
    const int tileX0 = blockIdx.x * TX;
    const int tileY0 = blockIdx.y * TY;
    const int img = blockIdx.z;
    const float* __restrict__ src = x + (size_t)img * (IMG_H * IMG_W);
    float* __restrict__ dst = out + (size_t)img * (IMG_H * IMG_W);

#ifdef HAVE_GLOAD_LDS
    // ---- async stage: 360 16B units over 4 waves (90 each = 64 + 26) ----
    {
        const int wv = tid >> 6;
        const int ln = tid & 63;
        const int u0 = wv * 90;
        {
            int u = u0 + ln;
            int r = u / UNITS_PER_ROW;
            int c = u - r * UNITS_PER_ROW;
            int gy = reflect_idx(tileY0 - HALO + r, IMG_H);
            int gxw = tileX0 - 4 + c * 4;
            gxw = max(gxw, 0); gxw = min(gxw, IMG_W - 4);
            async_copy16(src + gy * IMG_W + gxw, &tile[u0 * 4]);
        }
        if (ln < 26) {
            int u = u0 + 64 + ln;
            int r = u / UNITS_PER_ROW;
            int c = u - r * UNITS_PER_ROW;
            int gy = reflect_idx(tileY0 - HALO + r, IMG_H);
            int gxw = tileX0 - 4 + c * 4;
            gxw = max(gxw, 0); gxw = min(gxw, IMG_W - 4);
            async_copy16(src + gy * IMG_W + gxw, &tile[(u0 + 64) * 4]);
        }
    }
    __syncthreads();   // drains vmcnt -> gload_lds data visible

    // ---- x-border fixup: clamped loads put wrong values in 2 needed halo cols ----
    {
        const bool isL = (tileX0 == 0);
        const bool isR = (tileX0 == IMG_W - TX);
        if (isL | isR) {
            if (tid < 2 * LH) {
                int r = tid >> 1, k = tid & 1;
                int gy = reflect_idx(tileY0 - HALO + r, IMG_H);
                const float* srow = src + gy * IMG_W;
                if (isL) tile[r * LSTRIDE + 2 + k] = srow[2 - k];        // gx -2,-1 -> 2,1
                else     tile[r * LSTRIDE + 68 + k] = srow[510 - k];     // gx 512,513 -> 510,509
            }
            __syncthreads();
        }
    }
#else
    // fallback: float2-vectorized manual staging (cols 0..71, clamp+fixup-free reflect)
    for (int u = tid; u < LH * (LW / 2); u += 256) {
        int r = u / (LW / 2);
        int c = (u - r * (LW / 2)) * 2;
        int gy = reflect_idx(tileY0 - HALO + r, IMG_H);
        const float* srow = src + gy * IMG_W;
        int gx0 = tileX0 - 4 + c;
        float2 v;
        if (gx0 >= 0 && gx0 + 1 < IMG_W) {
            v = *reinterpret_cast<const float2*>(&srow[gx0]);
        } else {
            v.x = srow[reflect_idx(gx0, IMG_W)];
            v.y = srow[reflect_idx(gx0 + 1, IMG_W)];
        }
        *reinterpret_cast<float2*>(&tile[r * LSTRIDE + c]) = v;
    }
    __syncthreads();
#endif

    const int txg = tid & 15;      // thread x-group: 0..15
    const int ty  = tid >> 4;      // thread row:     0..15
    const int lxw = txg * PXT;     // first word of this thread's 3-quad read window

    const float RC = -72.13475204444817f;        // -1/(2*0.1^2) * log2(e)
    // L[r2] = -r2 * log2(e)/8, r2 in {1,2,4,5,8}
    const float L1 = -0.18033688011112043f;
    const float L2 = -0.36067376022224086f;
    const float L4 = -0.7213475204444817f;
    const float L5 = -0.9016844005556021f;
    const float L8 = -1.4426950408889634f;
    const v2f RCv = {RC, RC};

    // aligned b128 row reads: 12 words at (ty+dy)*72 + lxw (16B-aligned)
    auto ldrow = [&](int dy, v4f& Q0, v4f& Q1, v4f& Q2) {
        const v4f* p = reinterpret_cast<const v4f*>(&tile[(ty + dy) * LSTRIDE + lxw]);
        Q0 = p[0];
        Q1 = p[1];
        Q2 = p[2];
    };

    // center row (dy=2): pixels are exactly Q1 (words lxw+4..lxw+7)
    v4f Q20, Q21, Q22;
    ldrow(2, Q20, Q21, Q22);
    const v2f cA = {Q21[0], Q21[1]};
    const v2f cB = {Q21[2], Q21[3]};

    // per-pixel exponent-poly coefficients: arg = RC*n^2 + B*n + (C0 + L[r2])
    const v2f BA = cA * (-2.0f * RC);
    const v2f BB = cB * (-2.0f * RC);
    const v2f C0A = (cA * cA) * RC;
    const v2f C0B = (cB * cB) * RC;
    const v2f C1A = C0A + L1, C1B = C0B + L1;
    const v2f C2A = C0A + L2, C2B = C0B + L2;
    const v2f C4A = C0A + L4, C4B = C0B + L4;
    const v2f C5A = C0A + L5, C5B = C0B + L5;
    const v2f C8A = C0A + L8, C8B = C0B + L8;

    // center tap folded in: weight exactly 1
    v2f wsA = {1.0f, 1.0f}, wsB = {1.0f, 1.0f};
    v2f accA = cA, accB = cB;

    auto tap = [&](v2f nA, v2f nB, v2f CA, v2f CB) {
        v2f uA = __builtin_elementwise_fma(RCv, nA, BA);
        v2f tA = __builtin_elementwise_fma(uA, nA, CA);
        v2f uB = __builtin_elementwise_fma(RCv, nB, BB);
        v2f tB = __builtin_elementwise_fma(uB, nB, CB);
        v2f eA, eB;
        eA.x = FAST_EXP2(tA.x); eA.y = FAST_EXP2(tA.y);
        eB.x = FAST_EXP2(tB.x); eB.y = FAST_EXP2(tB.y);
        wsA += eA;
        wsB += eB;
        accA = __builtin_elementwise_fma(eA, nA, accA);
        accB = __builtin_elementwise_fma(eB, nB, accB);
    };

    // window pairs from Q0..Q2 (words w0..w11, taps use w2..w9):
    //  dx0:(E1,E2) dx1:(O1,O2) dx2:(E2,E3) dx3:(O2,O3) dx4:(E3,E4)
    auto dorow = [&](v4f Q0, v4f Q1, v4f Q2, v2f CaA, v2f CaB, v2f CbA, v2f CbB,
                     v2f CcA, v2f CcB, bool center_row) {
        v2f E1 = {Q0[2], Q0[3]};
        v2f E2 = {Q1[0], Q1[1]};
        v2f E3 = {Q1[2], Q1[3]};
        v2f E4 = {Q2[0], Q2[1]};
        v2f O1 = {Q0[3], Q1[0]};
        v2f O2 = {Q1[1], Q1[2]};
        v2f O3 = {Q1[3], Q2[0]};
        tap(E1, E2, CaA, CaB);                   // dx = 0
        tap(O1, O2, CbA, CbB);                   // dx = 1
        if (!center_row) tap(E2, E3, CcA, CcB);  // dx = 2 (non-center rows)
        tap(O2, O3, CbA, CbB);                   // dx = 3
        tap(E3, E4, CaA, CaB);                   // dx = 4
    };

    // dy = 2 first (row already loaded): r2 = {4,1,-,1,4}
    dorow(Q20, Q21, Q22, C4A, C4B, C1A, C1B, C1A, C1B, true);

    #pragma unroll
    for (int dy = 0; dy < KK; dy++) {
        if (dy == 2) continue;
        v4f Q0, Q1, Q2;
        ldrow(dy, Q0, Q1, Q2);
        if (dy == 0 || dy == 4) {
            // r2 = {8,5,4,5,8}
            dorow(Q0, Q1, Q2, C8A, C8B, C5A, C5B, C4A, C4B, false);
        } else {
            // r2 = {5,2,1,2,5}
            dorow(Q0, Q1, Q2, C5A, C5B, C2A, C2B, C1A, C1B, false);
        }
    }

    const int ox = tileX0 + txg * PXT;
    const int oy = tileY0 + ty;
    float4 o;
    o.x = accA.x * FAST_RCP(wsA.x);   // ws >= 1 (center tap), clip(1e-10) is dead
    o.y = accA.y * FAST_RCP(wsA.y);
    o.z = accB.x * FAST_RCP(wsB.x);
    o.w = accB.y * FAST_RCP(wsB.y);
    *reinterpret_cast<float4*>(&dst[oy * IMG_W + ox]) = o;
}

extern "C" void kernel_launch(void* const* d_in, const int* in_sizes, int n_in,
                              void* d_out, int out_size, void* d_ws, size_t ws_size,
                              hipStream_t stream) {
    const float* x = (const float*)d_in[0];
    // d_in[1] (spatial 5x5) is analytically exp(-(dx^2+dy^2)/8); folded into constants.
    float* out = (float*)d_out;

    const int n_img = out_size / (IMG_H * IMG_W);   // B*C = 24
    dim3 grid(IMG_W / TX, IMG_H / TY, n_img);       // (8, 32, 24)
    dim3 block(256);
    hipLaunchKernelGGL(bilateral_kernel, grid, block, 0, stream, x, out);
}